// Round 9
// baseline (393.522 us; speedup 1.0000x reference)
//
#include <hip/hip_runtime.h>

// Fused avg-pool(3x3,s2,p1,/9) + 8-neighbor rolled squared-dist + channel-sum + max.
// Fast path (dist==1): LDS holds 16 channels x 6 pooled rows x 128 cols (48 KiB).
// Per block: 4 chunks of { stream-fill LDS (no barriers, deep MLP) -> barrier ->
// accumulate 16 channels -> barrier }. 8 barriers total vs 128 in the per-channel
// design. One block = (batch, band of 4 quad rows), 512 threads, 1 thread per quad.
// Generic kernel (any dist<=5) also launched with device-side guard on dist.

#define NCH 16
#define PR1 6           // pooled rows per band, dist==1
#define QR  4

__global__ __launch_bounds__(512, 4) void fused1_k(const float* __restrict__ f,
                                                   float* __restrict__ out,
                                                   const int* __restrict__ distp) {
    if (*distp != 1) return;
    __shared__ __align__(16) float ps[NCH][PR1][128];

    const int band = blockIdx.x & 31;
    const int b    = blockIdx.x >> 5;
    const int ty0  = band * QR;
    const int tid  = threadIdx.x;
    const int qr   = tid >> 7;               // 0..3
    const int tx   = tid & 127;
    const int ty   = ty0 + qr;

    const float* fb = f + (size_t)b * 64 * 65536;
    const int foff = (2 * ty) * 256 + 2 * tx;
    const int cxm = (tx - 1) & 127;
    const int cxp = (tx + 1) & 127;

    float dot[4][8], sp2[8], sf2[4];
#pragma unroll
    for (int q = 0; q < 4; ++q) { sf2[q] = 0.f;
#pragma unroll
        for (int n = 0; n < 8; ++n) dot[q][n] = 0.f; }
#pragma unroll
    for (int n = 0; n < 8; ++n) sp2[n] = 0.f;

    for (int chunk = 0; chunk < 4; ++chunk) {
        const float* fcb = fb + (size_t)chunk * NCH * 65536;

        // ---- fill: 16ch x 6rows x 64 col-pairs = 6144 items / 512 thr = 12 each ----
#pragma unroll 4
        for (int k = 0; k < 12; ++k) {
            int idx = k * 512 + tid;
            int ch  = idx / 384;             // 384 = 6*64 items per channel
            int rem = idx - ch * 384;
            int r   = rem >> 6;              // pooled row 0..5
            int j   = rem & 63;              // pooled cols 2j, 2j+1
            int pr  = (ty0 - 1 + r) & 127;   // absolute pooled row (roll wrap)
            const float* fc = fcb + (size_t)ch * 65536;
            int y0 = 2 * pr - 1;
            float s0 = 0.f, s1 = 0.f;
#pragma unroll
            for (int ky = 0; ky < 3; ++ky) {
                int y = y0 + ky;
                if ((unsigned)y < 256u) {    // zero-pad at image boundary
                    const float* row = fc + y * 256 + 4 * j;
                    float  e = (j > 0) ? row[-1] : 0.f;
                    float4 v = *(const float4*)row;
                    s0 += e   + v.x + v.y;
                    s1 += v.y + v.z + v.w;
                }
            }
            *(float2*)&ps[ch][r][2 * j] =
                make_float2(s0 * (1.f / 9.f), s1 * (1.f / 9.f));
        }
        __syncthreads();                     // fill visible

        // ---- accumulate 16 channels; feature quad loaded 1 channel ahead ----
        float2 fa = *(const float2*)(fcb + foff);
        float2 fbq = *(const float2*)(fcb + foff + 256);
#pragma unroll 4
        for (int ch = 0; ch < NCH; ++ch) {
            float2 na = fa, nb = fbq;
            if (ch + 1 < NCH) {
                const float* fqn = fcb + (size_t)(ch + 1) * 65536 + foff;
                na = *(const float2*)(fqn);
                nb = *(const float2*)(fqn + 256);
            }
            float p[8];
            p[0] = ps[ch][qr    ][cxm]; p[1] = ps[ch][qr    ][tx]; p[2] = ps[ch][qr    ][cxp];
            p[3] = ps[ch][qr + 1][cxm];                            p[4] = ps[ch][qr + 1][cxp];
            p[5] = ps[ch][qr + 2][cxm]; p[6] = ps[ch][qr + 2][tx]; p[7] = ps[ch][qr + 2][cxp];

            float fv[4] = { fa.x, fa.y, fbq.x, fbq.y };
#pragma unroll
            for (int n = 0; n < 8; ++n) sp2[n] = fmaf(p[n], p[n], sp2[n]);
#pragma unroll
            for (int q = 0; q < 4; ++q) {
                float fq = fv[q];
                sf2[q] = fmaf(fq, fq, sf2[q]);
#pragma unroll
                for (int n = 0; n < 8; ++n) dot[q][n] = fmaf(fq, p[n], dot[q][n]);
            }
            fa = na; fbq = nb;
        }
        __syncthreads();                     // reads done before next fill
    }

    // ---- epilogue ----
    float res[4];
#pragma unroll
    for (int q = 0; q < 4; ++q) {
        float m = -3.4e38f;
#pragma unroll
        for (int n = 0; n < 8; ++n)
            m = fmaxf(m, fmaf(-2.f, dot[q][n], sf2[q] + sp2[n]));
        res[q] = m;
    }
    float* op = out + (size_t)b * 65536 + foff;
    *(float2*)(op)       = make_float2(res[0], res[1]);
    *(float2*)(op + 256) = make_float2(res[2], res[3]);
}

// ---------------- generic fallback (any dist <= 5), known-good R6 structure ------
#define MAXPR (QR + 10)

__global__ __launch_bounds__(512, 4) void fusedg_k(const float* __restrict__ f,
                                                   float* __restrict__ out,
                                                   const int* __restrict__ distp) {
    const int dist = *distp;
    if (dist == 1) return;                   // fast path handles dist==1
    __shared__ __align__(16) float ps[MAXPR][128];
    const int PR   = QR + 2 * dist;

    const int band = blockIdx.x & 31;
    const int b    = blockIdx.x >> 5;
    const int ty0  = band * QR;
    const int tid  = threadIdx.x;
    const int qr   = tid >> 7;
    const int tx   = tid & 127;
    const int ty   = ty0 + qr;

    for (int w = tid; w < MAXPR * 128; w += 512) ((float*)ps)[w] = 0.f;
    __syncthreads();

    const float* fb = f + (size_t)b * 64 * 65536;
    const int foff = (2 * ty) * 256 + 2 * tx;
    const int cxm = (tx - dist) & 127;
    const int cxp = (tx + dist) & 127;
    const int rm  = qr;
    const int rc  = qr + dist;
    const int rp  = qr + 2 * dist;

    float dot[4][8], sp2[8], sf2[4];
#pragma unroll
    for (int q = 0; q < 4; ++q) { sf2[q] = 0.f;
#pragma unroll
        for (int n = 0; n < 8; ++n) dot[q][n] = 0.f; }
#pragma unroll
    for (int n = 0; n < 8; ++n) sp2[n] = 0.f;

    for (int c = 0; c < 64; ++c) {
        const float* fc = fb + (size_t)c * 65536;
        for (int w = tid; w < PR * 64; w += 512) {
            int r = w >> 6, j = w & 63;
            int pr = (ty0 - dist + r) & 127;
            float s0 = 0.f, s1 = 0.f;
            int y0 = 2 * pr - 1;
#pragma unroll
            for (int ky = 0; ky < 3; ++ky) {
                int y = y0 + ky;
                if ((unsigned)y < 256u) {
                    const float* row = fc + y * 256 + 4 * j;
                    float  e = (j > 0) ? row[-1] : 0.f;
                    float4 v = *(const float4*)row;
                    s0 += e   + v.x + v.y;
                    s1 += v.y + v.z + v.w;
                }
            }
            *(float2*)&ps[r][2 * j] = make_float2(s0 * (1.f / 9.f), s1 * (1.f / 9.f));
        }
        __syncthreads();

        const float* fp = fc + foff;
        float2 q0 = *(const float2*)(fp);
        float2 q1 = *(const float2*)(fp + 256);
        float fv[4] = { q0.x, q0.y, q1.x, q1.y };
        float p[8];
        p[0] = ps[rm][cxm]; p[1] = ps[rm][tx]; p[2] = ps[rm][cxp];
        p[3] = ps[rc][cxm];                    p[4] = ps[rc][cxp];
        p[5] = ps[rp][cxm]; p[6] = ps[rp][tx]; p[7] = ps[rp][cxp];

#pragma unroll
        for (int n = 0; n < 8; ++n) sp2[n] = fmaf(p[n], p[n], sp2[n]);
#pragma unroll
        for (int q = 0; q < 4; ++q) {
            float fq = fv[q];
            sf2[q] = fmaf(fq, fq, sf2[q]);
#pragma unroll
            for (int n = 0; n < 8; ++n) dot[q][n] = fmaf(fq, p[n], dot[q][n]);
        }
        __syncthreads();
    }

    float res[4];
#pragma unroll
    for (int q = 0; q < 4; ++q) {
        float m = -3.4e38f;
#pragma unroll
        for (int n = 0; n < 8; ++n)
            m = fmaxf(m, fmaf(-2.f, dot[q][n], sf2[q] + sp2[n]));
        res[q] = m;
    }
    float* op = out + (size_t)b * 65536 + foff;
    *(float2*)(op)       = make_float2(res[0], res[1]);
    *(float2*)(op + 256) = make_float2(res[2], res[3]);
}

extern "C" void kernel_launch(void* const* d_in, const int* in_sizes, int n_in,
                              void* d_out, int out_size, void* d_ws, size_t ws_size,
                              hipStream_t stream) {
    const float* feature = (const float*)d_in[0];
    const int*   distp   = (const int*)d_in[1];
    float* out = (float*)d_out;

    // Both launched every call; each early-outs unless dist matches its case.
    fused1_k<<<512, 512, 0, stream>>>(feature, out, distp);
    fusedg_k<<<512, 512, 0, stream>>>(feature, out, distp);
}